// Round 9
// baseline (412.459 us; speedup 1.0000x reference)
//
#include <hip/hip_runtime.h>

#define NN 50000
#define FF 300
#define DD 128
#define HH 4
#define CC 32
#define EE 640000
#define RR 200
#define LL 2
#define SB ((NN + 255) / 256)   // scan blocks = 196
#define PK 320                  // proj K padded to multiple of 32

typedef unsigned short u16;
typedef unsigned int u32;
typedef unsigned long long u64;
typedef __attribute__((ext_vector_type(8))) short short8;   // 8 bf16 (4 VGPRs)
typedef __attribute__((ext_vector_type(4))) float floatx4;  // MFMA accumulator

__device__ __forceinline__ float bf2f(u16 u) {
    union { u32 i; float f; } v; v.i = ((u32)u) << 16; return v.f;
}
__device__ __forceinline__ u16 f2bf(float f) {
    u32 u = __float_as_uint(f);
    u32 r = (u >> 16) & 1u;
    u += 0x7fffu + r;
    return (u16)(u >> 16);
}
// unpack 2 bf16 from one u32 (lo = lower address = even channel)
__device__ __forceinline__ void bf2x(u32 p, float& lo, float& hi) {
    lo = __uint_as_float(p << 16);
    hi = __uint_as_float(p & 0xffff0000u);
}

// block-wide (256 threads) scan: returns exclusive prefix of v; *total = block sum
__device__ __forceinline__ int block_excl_scan(int v, int* lds4, int* total) {
    int lane = threadIdx.x & 63, wid = threadIdx.x >> 6;
    int x = v;
    #pragma unroll
    for (int off = 1; off < 64; off <<= 1) {
        int y = __shfl_up(x, off, 64);
        if (lane >= off) x += y;
    }
    if (lane == 63) lds4[wid] = x;
    __syncthreads();
    int add = 0;
    #pragma unroll
    for (int w = 0; w < 4; w++) add += (w < wid) ? lds4[w] : 0;
    *total = lds4[0] + lds4[1] + lds4[2] + lds4[3];
    return x + add - v;
}

// ---------------- weight transpose-convert: fp32 [K][128] -> bf16 WT [128][K]
// layout in wt: [proj 128xPK (zero-padded past FF)] [wl0][wl1][wr0][wr1] each 128x128
__global__ __launch_bounds__(256)
void wconv_kernel(const float* __restrict__ proj_w, const float* __restrict__ w_l,
                  const float* __restrict__ w_r, u16* __restrict__ wt)
{
    int i = blockIdx.x * 256 + threadIdx.x;
    const int total = 128 * PK + 4 * 128 * 128;
    if (i >= total) return;
    float v;
    if (i < 128 * PK) {
        int n = i / PK, k = i - n * PK;
        v = (k < FF) ? proj_w[(size_t)k * DD + n] : 0.f;
    } else {
        int j = i - 128 * PK;
        int seg = j >> 14;          // 16384 per segment: wl0, wl1, wr0, wr1
        int r = j & 16383;
        int n = r >> 7, k = r & 127;
        const float* src = (seg < 2) ? (w_l + (size_t)seg * DD * DD)
                                     : (w_r + (size_t)(seg - 2) * DD * DD);
        v = src[(size_t)k * DD + n];
    }
    wt[i] = f2bf(v);
}

// ---------------- relation projection (bf16 out)
__global__ __launch_bounds__(128)
void relproj_kernel(const float* __restrict__ rel_emb,
                    const float* __restrict__ w_e,
                    u16* __restrict__ erel)
{
    int lr = blockIdx.x;            // l*RR + r
    int l = lr / RR, r = lr - l * RR;
    int d = threadIdx.x;
    __shared__ float rv[DD];
    rv[d] = rel_emb[r * DD + d];
    __syncthreads();
    const float* W = w_e + (size_t)l * DD * DD;
    float acc = 0.f;
    #pragma unroll 8
    for (int k = 0; k < DD; k++) acc += rv[k] * W[k * DD + d];
    erel[(size_t)lr * DD + d] = f2bf(acc);
}

// ---------------- MFMA bf16 GEMM: C[M,128] = A[M,Ka] @ WT^T + bias, out bf16
// WT is pre-transposed bf16 [128][ldb] (k-major). K = padded loop bound (mult of 32).
// blockIdx.y selects (BT1,bias1,C1) or (BT2,bias2,C2).
template<bool ABF16, bool GATHER>
__global__ __launch_bounds__(256)
void gemm_mfma_kernel(const void* __restrict__ A_, const int* __restrict__ rowidx,
                      int lda, int K, int Ka, int ldb,
                      const u16* __restrict__ BT1, const float* __restrict__ bias1,
                      u16* __restrict__ C1,
                      const u16* __restrict__ BT2, const float* __restrict__ bias2,
                      u16* __restrict__ C2, int M)
{
    const u16*   BT   = (blockIdx.y == 0) ? BT1 : BT2;
    const float* bias = (blockIdx.y == 0) ? bias1 : bias2;
    u16*         Cout = (blockIdx.y == 0) ? C1 : C2;

    __shared__ u16 As[128][40];
    __shared__ u16 Bs[128][40];   // Bs[n][k]
    int tid  = threadIdx.x;
    int m0   = blockIdx.x * 128;
    int wave = tid >> 6, lane = tid & 63;
    int quad = lane >> 4, l16 = lane & 15;
    int wrow = (wave >> 1) * 64, wcol = (wave & 1) * 64;

    floatx4 acc[4][4];
    #pragma unroll
    for (int i = 0; i < 4; i++)
        #pragma unroll
        for (int j = 0; j < 4; j++) acc[i][j] = (floatx4){0.f, 0.f, 0.f, 0.f};

    int ar = tid >> 1, ahalf = tid & 1;
    int arow = m0 + ar;
    int rid = (arow < M) ? (GATHER ? rowidx[arow] : arow) : 0;

    for (int kk = 0; kk < K; kk += 32) {
        // ---- stage A (128 rows x 32 k), convert fp32->bf16 if needed
        {
            int kb = kk + ahalf * 16;
            u16 tmp[16];
            if (ABF16) {
                const u16* Ap = (const u16*)A_ + (size_t)rid * lda + kb;
                if (kb + 16 <= Ka) {
                    *(short8*)&tmp[0] = *(const short8*)Ap;
                    *(short8*)&tmp[8] = *(const short8*)(Ap + 8);
                } else {
                    #pragma unroll
                    for (int j = 0; j < 16; j++) tmp[j] = (kb + j < Ka) ? Ap[j] : (u16)0;
                }
            } else {
                const float* Ap = (const float*)A_ + (size_t)rid * lda + kb;
                if (kb + 16 <= Ka) {
                    #pragma unroll
                    for (int q = 0; q < 4; q++) {
                        float4 f = *(const float4*)(Ap + q * 4);
                        tmp[q*4+0] = f2bf(f.x); tmp[q*4+1] = f2bf(f.y);
                        tmp[q*4+2] = f2bf(f.z); tmp[q*4+3] = f2bf(f.w);
                    }
                } else {
                    #pragma unroll
                    for (int j = 0; j < 16; j++) tmp[j] = (kb + j < Ka) ? f2bf(Ap[j]) : (u16)0;
                }
            }
            *(short8*)&As[ar][ahalf * 16]     = *(short8*)&tmp[0];
            *(short8*)&As[ar][ahalf * 16 + 8] = *(short8*)&tmp[8];
        }
        // ---- stage B from pre-transposed bf16 WT: pure vector copies
        {
            const u16* Bp = BT + (size_t)ar * ldb + kk + ahalf * 16;
            *(short8*)&Bs[ar][ahalf * 16]     = *(const short8*)Bp;
            *(short8*)&Bs[ar][ahalf * 16 + 8] = *(const short8*)(Bp + 8);
        }
        __syncthreads();
        short8 af[4], bfr[4];
        #pragma unroll
        for (int i = 0; i < 4; i++)
            af[i] = *(const short8*)&As[wrow + i * 16 + l16][quad * 8];
        #pragma unroll
        for (int j = 0; j < 4; j++)
            bfr[j] = *(const short8*)&Bs[wcol + j * 16 + l16][quad * 8];
        #pragma unroll
        for (int i = 0; i < 4; i++)
            #pragma unroll
            for (int j = 0; j < 4; j++)
                acc[i][j] = __builtin_amdgcn_mfma_f32_16x16x32_bf16(
                    af[i], bfr[j], acc[i][j], 0, 0, 0);
        __syncthreads();
    }

    // epilogue: C/D layout col=lane&15, row=quad*4+reg (m89)
    #pragma unroll
    for (int i = 0; i < 4; i++) {
        #pragma unroll
        for (int rr = 0; rr < 4; rr++) {
            int row = m0 + wrow + i * 16 + quad * 4 + rr;
            if (row < M) {
                #pragma unroll
                for (int j = 0; j < 4; j++) {
                    int col = wcol + j * 16 + l16;
                    Cout[(size_t)row * DD + col] = f2bf(acc[i][j][rr] + bias[col]);
                }
            }
        }
    }
}

// ---------------- CSR build: histogram -> hierarchical scan -> scatter
__global__ __launch_bounds__(256)
void hist_kernel(const int* __restrict__ ei, int* __restrict__ counts)
{
    int e = blockIdx.x * 256 + threadIdx.x;
    if (e < EE) atomicAdd(&counts[ei[EE + e]], 1);
}

__global__ __launch_bounds__(256)
void scan_local_kernel(const int* __restrict__ counts, int* __restrict__ offsets,
                       int* __restrict__ bsum)
{
    __shared__ int lds4[4];
    int i = blockIdx.x * 256 + threadIdx.x;
    int v = (i < NN) ? counts[i] : 0;
    int total;
    int ex = block_excl_scan(v, lds4, &total);
    if (i < NN) offsets[i] = ex;
    if (threadIdx.x == 0) bsum[blockIdx.x] = total;
}

__global__ __launch_bounds__(256)
void scan_bsum_kernel(int* __restrict__ bsum)
{
    __shared__ int lds4[4];
    int t = threadIdx.x;
    int v = (t < SB) ? bsum[t] : 0;
    int total;
    int ex = block_excl_scan(v, lds4, &total);
    if (t < SB) bsum[t] = ex;
}

__global__ __launch_bounds__(256)
void scan_add_kernel(int* __restrict__ offsets, const int* __restrict__ bsum)
{
    int i = blockIdx.x * 256 + threadIdx.x;
    if (i < NN) offsets[i] += bsum[i >> 8];
    if (i == 0) offsets[NN] = EE;
}

__global__ __launch_bounds__(256)
void scatter_kernel(const int* __restrict__ ei, const int* __restrict__ et,
                    const int* __restrict__ offsets,
                    int* __restrict__ fill, int* __restrict__ srcp,
                    int* __restrict__ typep)
{
    int e = blockIdx.x * 256 + threadIdx.x;
    if (e >= EE) return;
    int d = ei[EE + e];
    int pos = offsets[d] + atomicAdd(&fill[d], 1);
    srcp[pos]  = ei[e];
    typep[pos] = et[e];
}

// ---------------- fused per-node: logits + softmax (no-shift) + aggregate + bias + act
// one wave per dst node; 8 edge-slots x 8 lanes; lane owns 16 channels (c0=(lane&7)*16)
// head of c = c>>5 -> head = gl>>1; head-dot completes with ONE shfl_xor(1).
__global__ __launch_bounds__(256)
void node_kernel(const int* __restrict__ srcp, const int* __restrict__ typep,
                 const int* __restrict__ offsets,
                 const u16* __restrict__ xl, const u16* __restrict__ xr,
                 const u16* __restrict__ erel, const float* __restrict__ att,
                 const float* __restrict__ bias,
                 u16* __restrict__ xnext, float* __restrict__ outp, int is_last)
{
    int tid  = threadIdx.x;
    int node = blockIdx.x * 4 + (tid >> 6);
    int lane = tid & 63;
    if (node >= NN) return;
    int g  = lane >> 3;          // edge slot 0..7
    int gl = lane & 7;           // channel group 0..7
    int c0 = gl * 16;
    int beg = offsets[node], end = offsets[node + 1];

    // per-node constants: xr 16ch + att 16ch in registers
    float xrf[16], attf[16];
    {
        const u32* xp = (const u32*)&xr[(size_t)node * DD + c0];
        #pragma unroll
        for (int q = 0; q < 8; q++) bf2x(xp[q], xrf[q*2], xrf[q*2+1]);
        #pragma unroll
        for (int q = 0; q < 4; q++) {
            float4 av = *(const float4*)&att[c0 + q * 4];
            attf[q*4]=av.x; attf[q*4+1]=av.y; attf[q*4+2]=av.z; attf[q*4+3]=av.w;
        }
    }

    float s = 0.f;
    float a[16];
    #pragma unroll
    for (int j = 0; j < 16; j++) a[j] = 0.f;

    for (int base = beg; base < end; base += 8) {
        int es = base + g;
        bool valid = es < end;
        int src = valid ? srcp[es] : 0;
        int typ = valid ? typep[es] : 0;
        const u32* xp = (const u32*)&xl[(size_t)src * DD + c0];
        const u32* ep = (const u32*)&erel[(size_t)typ * DD + c0];
        float xf[16], ef[16];
        #pragma unroll
        for (int q = 0; q < 8; q++) bf2x(xp[q], xf[q*2], xf[q*2+1]);
        #pragma unroll
        for (int q = 0; q < 8; q++) bf2x(ep[q], ef[q*2], ef[q*2+1]);
        float p = 0.f;
        #pragma unroll
        for (int j = 0; j < 16; j++) {
            float m = xf[j] + xrf[j] + ef[j];
            m = fmaxf(m, 0.2f * m);         // leaky_relu (slope<1): max(x, 0.2x)
            p += m * attf[j];
        }
        // complete 32-ch head dot: partner lane (gl^1) holds the other 16 ch
        p += __shfl_xor(p, 1, 64);
        // softmax without max-shift: logits are O(1); clamp guards inf
        float w = valid ? __expf(fminf(p, 60.f)) : 0.f;
        s += w;
        #pragma unroll
        for (int j = 0; j < 16; j++) a[j] += w * xf[j];
    }

    // reduce across the 8 edge slots (lane bits 3,4,5)
    #pragma unroll
    for (int j = 0; j < 16; j++) {
        a[j] += __shfl_xor(a[j], 8, 64);
        a[j] += __shfl_xor(a[j], 16, 64);
        a[j] += __shfl_xor(a[j], 32, 64);
    }
    s += __shfl_xor(s, 8, 64);
    s += __shfl_xor(s, 16, 64);
    s += __shfl_xor(s, 32, 64);

    if (lane < 8) {
        float rh = 1.f / fmaxf(s, 1e-30f);
        float v[16];
        #pragma unroll
        for (int q = 0; q < 4; q++) {
            float4 bv = *(const float4*)&bias[c0 + q * 4];
            v[q*4]   = a[q*4]   * rh + bv.x;
            v[q*4+1] = a[q*4+1] * rh + bv.y;
            v[q*4+2] = a[q*4+2] * rh + bv.z;
            v[q*4+3] = a[q*4+3] * rh + bv.w;
        }
        if (is_last) {
            float4* op = (float4*)&outp[(size_t)node * DD + c0];
            #pragma unroll
            for (int q = 0; q < 4; q++)
                op[q] = make_float4(v[q*4], v[q*4+1], v[q*4+2], v[q*4+3]);
        } else {
            u16 pk[16];
            #pragma unroll
            for (int j = 0; j < 16; j++) {
                float w2 = v[j] > 0.f ? v[j] : __expf(v[j]) - 1.f;   // elu
                pk[j] = f2bf(w2);
            }
            short8* xp = (short8*)&xnext[(size_t)node * DD + c0];
            xp[0] = *(short8*)&pk[0];
            xp[1] = *(short8*)&pk[8];
        }
    }
}

extern "C" void kernel_launch(void* const* d_in, const int* in_sizes, int n_in,
                              void* d_out, int out_size, void* d_ws, size_t ws_size,
                              hipStream_t stream)
{
    const int*   entity        = (const int*)d_in[0];
    const int*   edge_index    = (const int*)d_in[1];
    const int*   edge_type     = (const int*)d_in[2];
    const float* node_features = (const float*)d_in[3];
    const float* rel_emb       = (const float*)d_in[4];
    const float* proj_w        = (const float*)d_in[5];
    const float* proj_b        = (const float*)d_in[6];
    const float* w_l           = (const float*)d_in[7];
    const float* b_l           = (const float*)d_in[8];
    const float* w_r           = (const float*)d_in[9];
    const float* b_r           = (const float*)d_in[10];
    const float* w_e           = (const float*)d_in[11];
    const float* att           = (const float*)d_in[12];
    const float* bias          = (const float*)d_in[13];

    // workspace (~33 MB):
    u16*   xb     = (u16*)d_ws;                            // NN*DD bf16 (layer input)
    u16*   xl     = xb + (size_t)NN * DD;                  // NN*DD bf16
    u16*   xr     = xl + (size_t)NN * DD;                  // NN*DD bf16
    u16*   erel   = xr + (size_t)NN * DD;                  // LL*RR*DD bf16
    u16*   wt     = erel + (size_t)LL * RR * DD;           // 128*PK + 4*16384 bf16
    int*   srcp   = (int*)(wt + 128 * PK + 4 * 16384);     // EE int (src in dst-order)
    int*   typep  = srcp + (size_t)EE;                     // EE int
    int*   counts = typep + (size_t)EE;                    // NN int
    int*   fill   = counts + NN;                           // NN int
    int*   offsets= fill + NN;                             // NN+1 int
    int*   bsum   = offsets + NN + 1;                      // SB int

    // ---- CSR build (edges constant across layers: once per call)
    hipMemsetAsync(counts, 0, (size_t)NN * 2 * sizeof(int), stream);  // counts + fill
    hist_kernel<<<(EE + 255) / 256, 256, 0, stream>>>(edge_index, counts);
    scan_local_kernel<<<SB, 256, 0, stream>>>(counts, offsets, bsum);
    scan_bsum_kernel<<<1, 256, 0, stream>>>(bsum);
    scan_add_kernel<<<SB, 256, 0, stream>>>(offsets, bsum);
    scatter_kernel<<<(EE + 255) / 256, 256, 0, stream>>>(
        edge_index, edge_type, offsets, fill, srcp, typep);

    // ---- weights -> bf16 WT (once), relation projection
    const int WTOT = 128 * PK + 4 * 128 * 128;
    wconv_kernel<<<(WTOT + 255) / 256, 256, 0, stream>>>(proj_w, w_l, w_r, wt);
    relproj_kernel<<<LL * RR, 128, 0, stream>>>(rel_emb, w_e, erel);

    const u16* wtProj = wt;
    const int GB = (NN + 127) / 128;
    gemm_mfma_kernel<false, true><<<dim3(GB, 1), 256, 0, stream>>>(
        node_features, entity, FF, PK, FF, PK,
        wtProj, proj_b, xb, wtProj, proj_b, xb, NN);

    for (int l = 0; l < LL; l++) {
        const u16* wtl = wt + 128 * PK + l * 16384;
        const u16* wtr = wt + 128 * PK + 32768 + l * 16384;
        gemm_mfma_kernel<true, false><<<dim3(GB, 2), 256, 0, stream>>>(
            xb, nullptr, DD, DD, DD, DD,
            wtl, b_l + l * DD, xl,
            wtr, b_r + l * DD, xr, NN);

        node_kernel<<<(NN + 3) / 4, 256, 0, stream>>>(
            srcp, typep, offsets, xl, xr, erel + (size_t)l * RR * DD,
            att + (size_t)l * DD, bias + (size_t)l * DD,
            xb, (float*)d_out, l == LL - 1);
    }
}

// Round 10
// 370.075 us; speedup vs baseline: 1.1145x; 1.1145x over previous
//
#include <hip/hip_runtime.h>

#define NN 50000
#define FF 300
#define DD 128
#define HH 4
#define CC 32
#define EE 640000
#define RR 200
#define LL 2
#define SB ((NN + 255) / 256)   // scan blocks = 196
#define PK 320                  // proj K padded to multiple of 32

typedef unsigned short u16;
typedef unsigned int u32;
typedef unsigned long long u64;
typedef __attribute__((ext_vector_type(8))) short short8;   // 8 bf16 (4 VGPRs)
typedef __attribute__((ext_vector_type(4))) float floatx4;  // MFMA accumulator

__device__ __forceinline__ float bf2f(u16 u) {
    union { u32 i; float f; } v; v.i = ((u32)u) << 16; return v.f;
}
__device__ __forceinline__ u16 f2bf(float f) {
    u32 u = __float_as_uint(f);
    u32 r = (u >> 16) & 1u;
    u += 0x7fffu + r;
    return (u16)(u >> 16);
}
// unpack 2 bf16 from one u32 (lo = lower address = even channel)
__device__ __forceinline__ void bf2x(u32 p, float& lo, float& hi) {
    lo = __uint_as_float(p << 16);
    hi = __uint_as_float(p & 0xffff0000u);
}

// block-wide (256 threads) scan: returns exclusive prefix of v; *total = block sum
__device__ __forceinline__ int block_excl_scan(int v, int* lds4, int* total) {
    int lane = threadIdx.x & 63, wid = threadIdx.x >> 6;
    int x = v;
    #pragma unroll
    for (int off = 1; off < 64; off <<= 1) {
        int y = __shfl_up(x, off, 64);
        if (lane >= off) x += y;
    }
    if (lane == 63) lds4[wid] = x;
    __syncthreads();
    int add = 0;
    #pragma unroll
    for (int w = 0; w < 4; w++) add += (w < wid) ? lds4[w] : 0;
    *total = lds4[0] + lds4[1] + lds4[2] + lds4[3];
    return x + add - v;
}

// ---------------- weight transpose-convert: fp32 [K][128] -> bf16 WT [128][K]
// layout in wt: [proj 128xPK (zero-padded past FF)] [wl0][wl1][wr0][wr1] each 128x128
__global__ __launch_bounds__(256)
void wconv_kernel(const float* __restrict__ proj_w, const float* __restrict__ w_l,
                  const float* __restrict__ w_r, u16* __restrict__ wt)
{
    int i = blockIdx.x * 256 + threadIdx.x;
    const int total = 128 * PK + 4 * 128 * 128;
    if (i >= total) return;
    float v;
    if (i < 128 * PK) {
        int n = i / PK, k = i - n * PK;
        v = (k < FF) ? proj_w[(size_t)k * DD + n] : 0.f;
    } else {
        int j = i - 128 * PK;
        int seg = j >> 14;          // 16384 per segment: wl0, wl1, wr0, wr1
        int r = j & 16383;
        int n = r >> 7, k = r & 127;
        const float* src = (seg < 2) ? (w_l + (size_t)seg * DD * DD)
                                     : (w_r + (size_t)(seg - 2) * DD * DD);
        v = src[(size_t)k * DD + n];
    }
    wt[i] = f2bf(v);
}

// ---------------- relation projection (bf16 out)
__global__ __launch_bounds__(128)
void relproj_kernel(const float* __restrict__ rel_emb,
                    const float* __restrict__ w_e,
                    u16* __restrict__ erel)
{
    int lr = blockIdx.x;            // l*RR + r
    int l = lr / RR, r = lr - l * RR;
    int d = threadIdx.x;
    __shared__ float rv[DD];
    rv[d] = rel_emb[r * DD + d];
    __syncthreads();
    const float* W = w_e + (size_t)l * DD * DD;
    float acc = 0.f;
    #pragma unroll 8
    for (int k = 0; k < DD; k++) acc += rv[k] * W[k * DD + d];
    erel[(size_t)lr * DD + d] = f2bf(acc);
}

// ---------------- MFMA bf16 GEMM: C[M,128] = A[M,Ka] @ WT^T + bias, out bf16
// WT is pre-transposed bf16 [128][ldb] (k-major). K = padded loop bound (mult of 32).
// blockIdx.y selects (BT1,bias1,C1) or (BT2,bias2,C2).
template<bool ABF16, bool GATHER>
__global__ __launch_bounds__(256)
void gemm_mfma_kernel(const void* __restrict__ A_, const int* __restrict__ rowidx,
                      int lda, int K, int Ka, int ldb,
                      const u16* __restrict__ BT1, const float* __restrict__ bias1,
                      u16* __restrict__ C1,
                      const u16* __restrict__ BT2, const float* __restrict__ bias2,
                      u16* __restrict__ C2, int M)
{
    const u16*   BT   = (blockIdx.y == 0) ? BT1 : BT2;
    const float* bias = (blockIdx.y == 0) ? bias1 : bias2;
    u16*         Cout = (blockIdx.y == 0) ? C1 : C2;

    __shared__ u16 As[128][40];
    __shared__ u16 Bs[128][40];   // Bs[n][k]
    int tid  = threadIdx.x;
    int m0   = blockIdx.x * 128;
    int wave = tid >> 6, lane = tid & 63;
    int quad = lane >> 4, l16 = lane & 15;
    int wrow = (wave >> 1) * 64, wcol = (wave & 1) * 64;

    floatx4 acc[4][4];
    #pragma unroll
    for (int i = 0; i < 4; i++)
        #pragma unroll
        for (int j = 0; j < 4; j++) acc[i][j] = (floatx4){0.f, 0.f, 0.f, 0.f};

    int ar = tid >> 1, ahalf = tid & 1;
    int arow = m0 + ar;
    int rid = (arow < M) ? (GATHER ? rowidx[arow] : arow) : 0;

    for (int kk = 0; kk < K; kk += 32) {
        // ---- stage A (128 rows x 32 k), convert fp32->bf16 if needed
        {
            int kb = kk + ahalf * 16;
            u16 tmp[16];
            if (ABF16) {
                const u16* Ap = (const u16*)A_ + (size_t)rid * lda + kb;
                if (kb + 16 <= Ka) {
                    *(short8*)&tmp[0] = *(const short8*)Ap;
                    *(short8*)&tmp[8] = *(const short8*)(Ap + 8);
                } else {
                    #pragma unroll
                    for (int j = 0; j < 16; j++) tmp[j] = (kb + j < Ka) ? Ap[j] : (u16)0;
                }
            } else {
                const float* Ap = (const float*)A_ + (size_t)rid * lda + kb;
                if (kb + 16 <= Ka) {
                    #pragma unroll
                    for (int q = 0; q < 4; q++) {
                        float4 f = *(const float4*)(Ap + q * 4);
                        tmp[q*4+0] = f2bf(f.x); tmp[q*4+1] = f2bf(f.y);
                        tmp[q*4+2] = f2bf(f.z); tmp[q*4+3] = f2bf(f.w);
                    }
                } else {
                    #pragma unroll
                    for (int j = 0; j < 16; j++) tmp[j] = (kb + j < Ka) ? f2bf(Ap[j]) : (u16)0;
                }
            }
            *(short8*)&As[ar][ahalf * 16]     = *(short8*)&tmp[0];
            *(short8*)&As[ar][ahalf * 16 + 8] = *(short8*)&tmp[8];
        }
        // ---- stage B from pre-transposed bf16 WT: pure vector copies
        {
            const u16* Bp = BT + (size_t)ar * ldb + kk + ahalf * 16;
            *(short8*)&Bs[ar][ahalf * 16]     = *(const short8*)Bp;
            *(short8*)&Bs[ar][ahalf * 16 + 8] = *(const short8*)(Bp + 8);
        }
        __syncthreads();
        short8 af[4], bfr[4];
        #pragma unroll
        for (int i = 0; i < 4; i++)
            af[i] = *(const short8*)&As[wrow + i * 16 + l16][quad * 8];
        #pragma unroll
        for (int j = 0; j < 4; j++)
            bfr[j] = *(const short8*)&Bs[wcol + j * 16 + l16][quad * 8];
        #pragma unroll
        for (int i = 0; i < 4; i++)
            #pragma unroll
            for (int j = 0; j < 4; j++)
                acc[i][j] = __builtin_amdgcn_mfma_f32_16x16x32_bf16(
                    af[i], bfr[j], acc[i][j], 0, 0, 0);
        __syncthreads();
    }

    // epilogue: C/D layout col=lane&15, row=quad*4+reg (m89)
    #pragma unroll
    for (int i = 0; i < 4; i++) {
        #pragma unroll
        for (int rr = 0; rr < 4; rr++) {
            int row = m0 + wrow + i * 16 + quad * 4 + rr;
            if (row < M) {
                #pragma unroll
                for (int j = 0; j < 4; j++) {
                    int col = wcol + j * 16 + l16;
                    Cout[(size_t)row * DD + col] = f2bf(acc[i][j][rr] + bias[col]);
                }
            }
        }
    }
}

// ---------------- CSR build: histogram -> hierarchical scan -> scatter
__global__ __launch_bounds__(256)
void hist_kernel(const int* __restrict__ ei, int* __restrict__ counts)
{
    int e = blockIdx.x * 256 + threadIdx.x;
    if (e < EE) atomicAdd(&counts[ei[EE + e]], 1);
}

__global__ __launch_bounds__(256)
void scan_local_kernel(const int* __restrict__ counts, int* __restrict__ offsets,
                       int* __restrict__ bsum)
{
    __shared__ int lds4[4];
    int i = blockIdx.x * 256 + threadIdx.x;
    int v = (i < NN) ? counts[i] : 0;
    int total;
    int ex = block_excl_scan(v, lds4, &total);
    if (i < NN) offsets[i] = ex;
    if (threadIdx.x == 0) bsum[blockIdx.x] = total;
}

__global__ __launch_bounds__(256)
void scan_bsum_kernel(int* __restrict__ bsum)
{
    __shared__ int lds4[4];
    int t = threadIdx.x;
    int v = (t < SB) ? bsum[t] : 0;
    int total;
    int ex = block_excl_scan(v, lds4, &total);
    if (t < SB) bsum[t] = ex;
}

__global__ __launch_bounds__(256)
void scan_add_kernel(int* __restrict__ offsets, const int* __restrict__ bsum)
{
    int i = blockIdx.x * 256 + threadIdx.x;
    if (i < NN) offsets[i] += bsum[i >> 8];
    if (i == 0) offsets[NN] = EE;
}

__global__ __launch_bounds__(256)
void scatter_kernel(const int* __restrict__ ei, const int* __restrict__ et,
                    const int* __restrict__ offsets,
                    int* __restrict__ fill, int* __restrict__ srcp,
                    int* __restrict__ typep)
{
    int e = blockIdx.x * 256 + threadIdx.x;
    if (e >= EE) return;
    int d = ei[EE + e];
    int pos = offsets[d] + atomicAdd(&fill[d], 1);
    srcp[pos]  = ei[e];
    typep[pos] = et[e];
}

// ---------------- fused per-node: logits + softmax (no-shift) + aggregate + bias + act
// one wave per dst node; 4 edge-groups of 16 lanes; lane owns 8 channels (c0=(lane&15)*8)
// [R9 post-mortem: the 8x8 variant cost VGPR 32->56, occupancy 63%->35%, +24us. Keep 4x16.]
__global__ __launch_bounds__(256)
void node_kernel(const int* __restrict__ srcp, const int* __restrict__ typep,
                 const int* __restrict__ offsets,
                 const u16* __restrict__ xl, const u16* __restrict__ xr,
                 const u16* __restrict__ erel, const float* __restrict__ att,
                 const float* __restrict__ bias,
                 u16* __restrict__ xnext, float* __restrict__ outp, int is_last)
{
    int tid  = threadIdx.x;
    int node = blockIdx.x * 4 + (tid >> 6);
    int lane = tid & 63;
    if (node >= NN) return;
    int g  = lane >> 4;          // edge slot within quad
    int gl = lane & 15;          // channel set
    int c0 = gl * 8;
    int beg = offsets[node], end = offsets[node + 1];

    // per-node constants: xr channels + att channels (registers)
    float xrf[8], attf[8];
    {
        const u32* xp = (const u32*)&xr[(size_t)node * DD + c0];
        #pragma unroll
        for (int q = 0; q < 4; q++) bf2x(xp[q], xrf[q*2], xrf[q*2+1]);
        float4 a0 = *(const float4*)&att[c0];
        float4 a1 = *(const float4*)&att[c0 + 4];
        attf[0]=a0.x; attf[1]=a0.y; attf[2]=a0.z; attf[3]=a0.w;
        attf[4]=a1.x; attf[5]=a1.y; attf[6]=a1.z; attf[7]=a1.w;
    }

    float s = 0.f;
    float a[8];
    #pragma unroll
    for (int j = 0; j < 8; j++) a[j] = 0.f;

    for (int base = beg; base < end; base += 4) {
        int es = base + g;
        bool valid = es < end;
        int src = valid ? srcp[es] : 0;
        int typ = valid ? typep[es] : 0;
        const u32* xp = (const u32*)&xl[(size_t)src * DD + c0];
        const u32* ep = (const u32*)&erel[(size_t)typ * DD + c0];
        u32 xv0 = xp[0], xv1 = xp[1], xv2 = xp[2], xv3 = xp[3];
        u32 ev0 = ep[0], ev1 = ep[1], ev2 = ep[2], ev3 = ep[3];
        float xf[8], ef[8];
        bf2x(xv0, xf[0], xf[1]); bf2x(xv1, xf[2], xf[3]);
        bf2x(xv2, xf[4], xf[5]); bf2x(xv3, xf[6], xf[7]);
        bf2x(ev0, ef[0], ef[1]); bf2x(ev1, ef[2], ef[3]);
        bf2x(ev2, ef[4], ef[5]); bf2x(ev3, ef[6], ef[7]);
        float p = 0.f;
        #pragma unroll
        for (int j = 0; j < 8; j++) {
            float m = xf[j] + xrf[j] + ef[j];
            m = fmaxf(m, 0.2f * m);         // leaky_relu (slope<1): max(x, 0.2x)
            p += m * attf[j];
        }
        // per-head logit: reduce over the 4 lanes of this head (gl span of 4)
        p += __shfl_xor(p, 1, 64);
        p += __shfl_xor(p, 2, 64);
        // softmax without max-shift: logits are O(1); clamp guards inf
        float w = valid ? __expf(fminf(p, 60.f)) : 0.f;
        s += w;
        #pragma unroll
        for (int j = 0; j < 8; j++) a[j] += w * xf[j];
    }

    // cross-group reduction (groups processed disjoint edges)
    #pragma unroll
    for (int j = 0; j < 8; j++) {
        a[j] += __shfl_xor(a[j], 16, 64);
        a[j] += __shfl_xor(a[j], 32, 64);
    }
    s += __shfl_xor(s, 16, 64);
    s += __shfl_xor(s, 32, 64);

    if (lane < 16) {
        float rh = 1.f / fmaxf(s, 1e-30f);
        float4 b0 = *(const float4*)&bias[c0];
        float4 b1 = *(const float4*)&bias[c0 + 4];
        float bv[8] = {b0.x, b0.y, b0.z, b0.w, b1.x, b1.y, b1.z, b1.w};
        float v[8];
        #pragma unroll
        for (int j = 0; j < 8; j++) v[j] = a[j] * rh + bv[j];
        if (is_last) {
            float4* op = (float4*)&outp[(size_t)node * DD + c0];
            op[0] = make_float4(v[0], v[1], v[2], v[3]);
            op[1] = make_float4(v[4], v[5], v[6], v[7]);
        } else {
            u16 pk[8];
            #pragma unroll
            for (int j = 0; j < 8; j++) {
                float w2 = v[j] > 0.f ? v[j] : __expf(v[j]) - 1.f;   // elu
                pk[j] = f2bf(w2);
            }
            *(short8*)&xnext[(size_t)node * DD + c0] = *(short8*)pk;
        }
    }
}

extern "C" void kernel_launch(void* const* d_in, const int* in_sizes, int n_in,
                              void* d_out, int out_size, void* d_ws, size_t ws_size,
                              hipStream_t stream)
{
    const int*   entity        = (const int*)d_in[0];
    const int*   edge_index    = (const int*)d_in[1];
    const int*   edge_type     = (const int*)d_in[2];
    const float* node_features = (const float*)d_in[3];
    const float* rel_emb       = (const float*)d_in[4];
    const float* proj_w        = (const float*)d_in[5];
    const float* proj_b        = (const float*)d_in[6];
    const float* w_l           = (const float*)d_in[7];
    const float* b_l           = (const float*)d_in[8];
    const float* w_r           = (const float*)d_in[9];
    const float* b_r           = (const float*)d_in[10];
    const float* w_e           = (const float*)d_in[11];
    const float* att           = (const float*)d_in[12];
    const float* bias          = (const float*)d_in[13];

    // workspace (~33 MB):
    u16*   xb     = (u16*)d_ws;                            // NN*DD bf16 (layer input)
    u16*   xl     = xb + (size_t)NN * DD;                  // NN*DD bf16
    u16*   xr     = xl + (size_t)NN * DD;                  // NN*DD bf16
    u16*   erel   = xr + (size_t)NN * DD;                  // LL*RR*DD bf16
    u16*   wt     = erel + (size_t)LL * RR * DD;           // 128*PK + 4*16384 bf16
    int*   srcp   = (int*)(wt + 128 * PK + 4 * 16384);     // EE int (src in dst-order)
    int*   typep  = srcp + (size_t)EE;                     // EE int
    int*   counts = typep + (size_t)EE;                    // NN int
    int*   fill   = counts + NN;                           // NN int
    int*   offsets= fill + NN;                             // NN+1 int
    int*   bsum   = offsets + NN + 1;                      // SB int

    // ---- CSR build (edges constant across layers: once per call)
    hipMemsetAsync(counts, 0, (size_t)NN * 2 * sizeof(int), stream);  // counts + fill
    hist_kernel<<<(EE + 255) / 256, 256, 0, stream>>>(edge_index, counts);
    scan_local_kernel<<<SB, 256, 0, stream>>>(counts, offsets, bsum);
    scan_bsum_kernel<<<1, 256, 0, stream>>>(bsum);
    scan_add_kernel<<<SB, 256, 0, stream>>>(offsets, bsum);
    scatter_kernel<<<(EE + 255) / 256, 256, 0, stream>>>(
        edge_index, edge_type, offsets, fill, srcp, typep);

    // ---- weights -> bf16 WT (once), relation projection
    const int WTOT = 128 * PK + 4 * 128 * 128;
    wconv_kernel<<<(WTOT + 255) / 256, 256, 0, stream>>>(proj_w, w_l, w_r, wt);
    relproj_kernel<<<LL * RR, 128, 0, stream>>>(rel_emb, w_e, erel);

    const u16* wtProj = wt;
    const int GB = (NN + 127) / 128;
    gemm_mfma_kernel<false, true><<<dim3(GB, 1), 256, 0, stream>>>(
        node_features, entity, FF, PK, FF, PK,
        wtProj, proj_b, xb, wtProj, proj_b, xb, NN);

    for (int l = 0; l < LL; l++) {
        const u16* wtl = wt + 128 * PK + l * 16384;
        const u16* wtr = wt + 128 * PK + 32768 + l * 16384;
        gemm_mfma_kernel<true, false><<<dim3(GB, 2), 256, 0, stream>>>(
            xb, nullptr, DD, DD, DD, DD,
            wtl, b_l + l * DD, xl,
            wtr, b_r + l * DD, xr, NN);

        node_kernel<<<(NN + 3) / 4, 256, 0, stream>>>(
            srcp, typep, offsets, xl, xr, erel + (size_t)l * RR * DD,
            att + (size_t)l * DD, bias + (size_t)l * DD,
            xb, (float*)d_out, l == LL - 1);
    }
}

// Round 11
// 338.673 us; speedup vs baseline: 1.2179x; 1.0927x over previous
//
#include <hip/hip_runtime.h>

#define NN 50000
#define FF 300
#define DD 128
#define HH 4
#define CC 32
#define EE 640000
#define RR 200
#define LL 2
#define SB ((NN + 255) / 256)     // scan blocks = 196
#define PK 320                    // proj K padded to multiple of 64
#define WTOT (128 * PK + 4 * 128 * 128)
#define HB ((EE + 255) / 256)     // hist blocks in prep
#define WB ((WTOT + 255) / 256)   // wconv blocks in prep
#define RB (LL * RR / 2)          // relproj blocks in prep (2 lr per block)

typedef unsigned short u16;
typedef unsigned int u32;
typedef __attribute__((ext_vector_type(8))) short short8;   // 8 bf16 (4 VGPRs)
typedef __attribute__((ext_vector_type(4))) float floatx4;  // MFMA accumulator

__device__ __forceinline__ float bf2f(u16 u) {
    union { u32 i; float f; } v; v.i = ((u32)u) << 16; return v.f;
}
__device__ __forceinline__ u16 f2bf(float f) {
    u32 u = __float_as_uint(f);
    u32 r = (u >> 16) & 1u;
    u += 0x7fffu + r;
    return (u16)(u >> 16);
}
// unpack 2 bf16 from one u32 (lo = lower address = even channel)
__device__ __forceinline__ void bf2x(u32 p, float& lo, float& hi) {
    lo = __uint_as_float(p << 16);
    hi = __uint_as_float(p & 0xffff0000u);
}

// block-wide (256 threads) scan: returns exclusive prefix of v; *total = block sum
__device__ __forceinline__ int block_excl_scan(int v, int* lds4, int* total) {
    int lane = threadIdx.x & 63, wid = threadIdx.x >> 6;
    int x = v;
    #pragma unroll
    for (int off = 1; off < 64; off <<= 1) {
        int y = __shfl_up(x, off, 64);
        if (lane >= off) x += y;
    }
    if (lane == 63) lds4[wid] = x;
    __syncthreads();
    int add = 0;
    #pragma unroll
    for (int w = 0; w < 4; w++) add += (w < wid) ? lds4[w] : 0;
    *total = lds4[0] + lds4[1] + lds4[2] + lds4[3];
    return x + add - v;
}

// ---------------- fused prep: hist | weight transpose-convert | relation projection
// (three independent jobs, selected by blockIdx range — branch is block-uniform)
__global__ __launch_bounds__(256)
void prep_kernel(const int* __restrict__ ei, int* __restrict__ counts,
                 const float* __restrict__ proj_w, const float* __restrict__ w_l,
                 const float* __restrict__ w_r, u16* __restrict__ wt,
                 const float* __restrict__ rel_emb, const float* __restrict__ w_e,
                 u16* __restrict__ erel)
{
    __shared__ float rv[2][DD];
    int b = blockIdx.x, tid = threadIdx.x;
    if (b < HB) {
        // degree histogram
        int e = b * 256 + tid;
        if (e < EE) atomicAdd(&counts[ei[EE + e]], 1);
    } else if (b < HB + WB) {
        // fp32 [K][128] -> bf16 WT [128][K]: [proj 128xPK pad0] [wl0][wl1][wr0][wr1]
        int i = (b - HB) * 256 + tid;
        if (i < WTOT) {
            float v;
            if (i < 128 * PK) {
                int n = i / PK, k = i - n * PK;
                v = (k < FF) ? proj_w[(size_t)k * DD + n] : 0.f;
            } else {
                int j = i - 128 * PK;
                int seg = j >> 14;          // wl0, wl1, wr0, wr1
                int r = j & 16383;
                int n = r >> 7, k = r & 127;
                const float* src = (seg < 2) ? (w_l + (size_t)seg * DD * DD)
                                             : (w_r + (size_t)(seg - 2) * DD * DD);
                v = src[(size_t)k * DD + n];
            }
            wt[i] = f2bf(v);
        }
    } else {
        // erel[l*RR+r][d] = rel_emb[r,:] @ w_e[l][:,d]   (2 lr per block)
        int half = tid >> 7, d = tid & 127;
        int lr = (b - HB - WB) * 2 + half;
        int l = lr / RR, r = lr - l * RR;
        rv[half][d] = rel_emb[r * DD + d];
        __syncthreads();
        const float* W = w_e + (size_t)l * DD * DD;
        float acc = 0.f;
        #pragma unroll 8
        for (int k = 0; k < DD; k++) acc += rv[half][k] * W[k * DD + d];
        erel[(size_t)lr * DD + d] = f2bf(acc);
    }
}

// ---------------- MFMA bf16 GEMM, BK=64: C[M,128] = A[M,Ka] @ WT^T + bias, out bf16
// WT pre-transposed bf16 [128][ldb] (k-major). K = padded loop bound (mult of 64).
// blockIdx.y selects (BT1,bias1,C1) or (BT2,bias2,C2).
template<bool ABF16, bool GATHER>
__global__ __launch_bounds__(256)
void gemm_mfma_kernel(const void* __restrict__ A_, const int* __restrict__ rowidx,
                      int lda, int K, int Ka, int ldb,
                      const u16* __restrict__ BT1, const float* __restrict__ bias1,
                      u16* __restrict__ C1,
                      const u16* __restrict__ BT2, const float* __restrict__ bias2,
                      u16* __restrict__ C2, int M)
{
    const u16*   BT   = (blockIdx.y == 0) ? BT1 : BT2;
    const float* bias = (blockIdx.y == 0) ? bias1 : bias2;
    u16*         Cout = (blockIdx.y == 0) ? C1 : C2;

    // pad 8 u16 -> 144 B rows: bank stride 4, 2-way conflicts only (free, m136)
    __shared__ u16 As[128][72];
    __shared__ u16 Bs[128][72];   // Bs[n][k]
    int tid  = threadIdx.x;
    int m0   = blockIdx.x * 128;
    int wave = tid >> 6, lane = tid & 63;
    int quad = lane >> 4, l16 = lane & 15;
    int wrow = (wave >> 1) * 64, wcol = (wave & 1) * 64;

    floatx4 acc[4][4];
    #pragma unroll
    for (int i = 0; i < 4; i++)
        #pragma unroll
        for (int j = 0; j < 4; j++) acc[i][j] = (floatx4){0.f, 0.f, 0.f, 0.f};

    int ar = tid >> 1, ah = tid & 1;   // row, k-half (32 each)
    int arow = m0 + ar;
    int rid = (arow < M) ? (GATHER ? rowidx[arow] : arow) : 0;

    for (int kk = 0; kk < K; kk += 64) {
        // ---- stage A (128 rows x 64 k), convert fp32->bf16 if needed
        #pragma unroll
        for (int q = 0; q < 2; q++) {
            int kb = kk + ah * 32 + q * 16;
            u16 tmp[16];
            if (ABF16) {
                const u16* Ap = (const u16*)A_ + (size_t)rid * lda + kb;
                if (kb + 16 <= Ka) {
                    *(short8*)&tmp[0] = *(const short8*)Ap;
                    *(short8*)&tmp[8] = *(const short8*)(Ap + 8);
                } else {
                    #pragma unroll
                    for (int j = 0; j < 16; j++) tmp[j] = (kb + j < Ka) ? Ap[j] : (u16)0;
                }
            } else {
                const float* Ap = (const float*)A_ + (size_t)rid * lda + kb;
                if (kb + 16 <= Ka) {
                    #pragma unroll
                    for (int qq = 0; qq < 4; qq++) {
                        float4 f = *(const float4*)(Ap + qq * 4);
                        tmp[qq*4+0] = f2bf(f.x); tmp[qq*4+1] = f2bf(f.y);
                        tmp[qq*4+2] = f2bf(f.z); tmp[qq*4+3] = f2bf(f.w);
                    }
                } else {
                    #pragma unroll
                    for (int j = 0; j < 16; j++) tmp[j] = (kb + j < Ka) ? f2bf(Ap[j]) : (u16)0;
                }
            }
            *(short8*)&As[ar][ah * 32 + q * 16]     = *(short8*)&tmp[0];
            *(short8*)&As[ar][ah * 32 + q * 16 + 8] = *(short8*)&tmp[8];
        }
        // ---- stage B from pre-transposed bf16 WT: pure vector copies
        {
            const u16* Bp = BT + (size_t)ar * ldb + kk + ah * 32;
            #pragma unroll
            for (int q = 0; q < 4; q++)
                *(short8*)&Bs[ar][ah * 32 + q * 8] = *(const short8*)(Bp + q * 8);
        }
        __syncthreads();
        #pragma unroll
        for (int ks = 0; ks < 2; ks++) {
            short8 af[4], bfr[4];
            #pragma unroll
            for (int i = 0; i < 4; i++)
                af[i] = *(const short8*)&As[wrow + i * 16 + l16][ks * 32 + quad * 8];
            #pragma unroll
            for (int j = 0; j < 4; j++)
                bfr[j] = *(const short8*)&Bs[wcol + j * 16 + l16][ks * 32 + quad * 8];
            #pragma unroll
            for (int i = 0; i < 4; i++)
                #pragma unroll
                for (int j = 0; j < 4; j++)
                    acc[i][j] = __builtin_amdgcn_mfma_f32_16x16x32_bf16(
                        af[i], bfr[j], acc[i][j], 0, 0, 0);
        }
        __syncthreads();
    }

    // epilogue: C/D layout col=lane&15, row=quad*4+reg (m89)
    #pragma unroll
    for (int i = 0; i < 4; i++) {
        #pragma unroll
        for (int rr = 0; rr < 4; rr++) {
            int row = m0 + wrow + i * 16 + quad * 4 + rr;
            if (row < M) {
                #pragma unroll
                for (int j = 0; j < 4; j++) {
                    int col = wcol + j * 16 + l16;
                    Cout[(size_t)row * DD + col] = f2bf(acc[i][j][rr] + bias[col]);
                }
            }
        }
    }
}

// ---------------- CSR scan (hierarchical) + scatter (packed src|type)
__global__ __launch_bounds__(256)
void scan_local_kernel(const int* __restrict__ counts, int* __restrict__ offsets,
                       int* __restrict__ bsum)
{
    __shared__ int lds4[4];
    int i = blockIdx.x * 256 + threadIdx.x;
    int v = (i < NN) ? counts[i] : 0;
    int total;
    int ex = block_excl_scan(v, lds4, &total);
    if (i < NN) offsets[i] = ex;
    if (threadIdx.x == 0) bsum[blockIdx.x] = total;
}

__global__ __launch_bounds__(256)
void scan_bsum_kernel(int* __restrict__ bsum)
{
    __shared__ int lds4[4];
    int t = threadIdx.x;
    int v = (t < SB) ? bsum[t] : 0;
    int total;
    int ex = block_excl_scan(v, lds4, &total);
    if (t < SB) bsum[t] = ex;
}

__global__ __launch_bounds__(256)
void scan_add_kernel(int* __restrict__ offsets, const int* __restrict__ bsum)
{
    int i = blockIdx.x * 256 + threadIdx.x;
    if (i < NN) offsets[i] += bsum[i >> 8];
    if (i == 0) offsets[NN] = EE;
}

// one random 4B write per edge (src 16b | type 16b packed; N<65536, R<256)
__global__ __launch_bounds__(256)
void scatter_kernel(const int* __restrict__ ei, const int* __restrict__ et,
                    const int* __restrict__ offsets,
                    int* __restrict__ fill, u32* __restrict__ dstorder)
{
    int e = blockIdx.x * 256 + threadIdx.x;
    if (e >= EE) return;
    int d = ei[EE + e];
    int pos = offsets[d] + atomicAdd(&fill[d], 1);
    dstorder[pos] = (u32)ei[e] | ((u32)et[e] << 16);
}

// ---------------- fused per-node: logits + softmax (no-shift) + aggregate + bias + act
// one wave per dst node; 4 edge-groups of 16 lanes; lane owns 8 channels (c0=(lane&15)*8)
// [R9 post-mortem: 8x8 variant cost VGPR 32->56, occupancy 63%->35%, +24us. Keep 4x16.]
__global__ __launch_bounds__(256)
void node_kernel(const u32* __restrict__ dstorder, const int* __restrict__ offsets,
                 const u16* __restrict__ xl, const u16* __restrict__ xr,
                 const u16* __restrict__ erel, const float* __restrict__ att,
                 const float* __restrict__ bias,
                 u16* __restrict__ xnext, float* __restrict__ outp, int is_last)
{
    int tid  = threadIdx.x;
    int node = blockIdx.x * 4 + (tid >> 6);
    int lane = tid & 63;
    if (node >= NN) return;
    int g  = lane >> 4;          // edge slot within quad
    int gl = lane & 15;          // channel set
    int c0 = gl * 8;
    int beg = offsets[node], end = offsets[node + 1];

    // per-node constants: xr channels + att channels (registers)
    float xrf[8], attf[8];
    {
        const u32* xp = (const u32*)&xr[(size_t)node * DD + c0];
        #pragma unroll
        for (int q = 0; q < 4; q++) bf2x(xp[q], xrf[q*2], xrf[q*2+1]);
        float4 a0 = *(const float4*)&att[c0];
        float4 a1 = *(const float4*)&att[c0 + 4];
        attf[0]=a0.x; attf[1]=a0.y; attf[2]=a0.z; attf[3]=a0.w;
        attf[4]=a1.x; attf[5]=a1.y; attf[6]=a1.z; attf[7]=a1.w;
    }

    float s = 0.f;
    float a[8];
    #pragma unroll
    for (int j = 0; j < 8; j++) a[j] = 0.f;

    for (int base = beg; base < end; base += 4) {
        int es = base + g;
        bool valid = es < end;
        u32 st = valid ? dstorder[es] : 0;
        int src = st & 0xffff;
        int typ = st >> 16;
        const u32* xp = (const u32*)&xl[(size_t)src * DD + c0];
        const u32* ep = (const u32*)&erel[(size_t)typ * DD + c0];
        u32 xv0 = xp[0], xv1 = xp[1], xv2 = xp[2], xv3 = xp[3];
        u32 ev0 = ep[0], ev1 = ep[1], ev2 = ep[2], ev3 = ep[3];
        float xf[8], ef[8];
        bf2x(xv0, xf[0], xf[1]); bf2x(xv1, xf[2], xf[3]);
        bf2x(xv2, xf[4], xf[5]); bf2x(xv3, xf[6], xf[7]);
        bf2x(ev0, ef[0], ef[1]); bf2x(ev1, ef[2], ef[3]);
        bf2x(ev2, ef[4], ef[5]); bf2x(ev3, ef[6], ef[7]);
        float p = 0.f;
        #pragma unroll
        for (int j = 0; j < 8; j++) {
            float m = xf[j] + xrf[j] + ef[j];
            m = fmaxf(m, 0.2f * m);         // leaky_relu (slope<1): max(x, 0.2x)
            p += m * attf[j];
        }
        // per-head logit: reduce over the 4 lanes of this head (gl span of 4)
        p += __shfl_xor(p, 1, 64);
        p += __shfl_xor(p, 2, 64);
        // softmax without max-shift: logits are O(1); clamp guards inf
        float w = valid ? __expf(fminf(p, 60.f)) : 0.f;
        s += w;
        #pragma unroll
        for (int j = 0; j < 8; j++) a[j] += w * xf[j];
    }

    // cross-group reduction (groups processed disjoint edges)
    #pragma unroll
    for (int j = 0; j < 8; j++) {
        a[j] += __shfl_xor(a[j], 16, 64);
        a[j] += __shfl_xor(a[j], 32, 64);
    }
    s += __shfl_xor(s, 16, 64);
    s += __shfl_xor(s, 32, 64);

    if (lane < 16) {
        float rh = 1.f / fmaxf(s, 1e-30f);
        float4 b0 = *(const float4*)&bias[c0];
        float4 b1 = *(const float4*)&bias[c0 + 4];
        float bv[8] = {b0.x, b0.y, b0.z, b0.w, b1.x, b1.y, b1.z, b1.w};
        float v[8];
        #pragma unroll
        for (int j = 0; j < 8; j++) v[j] = a[j] * rh + bv[j];
        if (is_last) {
            float4* op = (float4*)&outp[(size_t)node * DD + c0];
            op[0] = make_float4(v[0], v[1], v[2], v[3]);
            op[1] = make_float4(v[4], v[5], v[6], v[7]);
        } else {
            u16 pk[8];
            #pragma unroll
            for (int j = 0; j < 8; j++) {
                float w2 = v[j] > 0.f ? v[j] : __expf(v[j]) - 1.f;   // elu
                pk[j] = f2bf(w2);
            }
            *(short8*)&xnext[(size_t)node * DD + c0] = *(short8*)pk;
        }
    }
}

extern "C" void kernel_launch(void* const* d_in, const int* in_sizes, int n_in,
                              void* d_out, int out_size, void* d_ws, size_t ws_size,
                              hipStream_t stream)
{
    const int*   entity        = (const int*)d_in[0];
    const int*   edge_index    = (const int*)d_in[1];
    const int*   edge_type     = (const int*)d_in[2];
    const float* node_features = (const float*)d_in[3];
    const float* rel_emb       = (const float*)d_in[4];
    const float* proj_w        = (const float*)d_in[5];
    const float* proj_b        = (const float*)d_in[6];
    const float* w_l           = (const float*)d_in[7];
    const float* b_l           = (const float*)d_in[8];
    const float* w_r           = (const float*)d_in[9];
    const float* b_r           = (const float*)d_in[10];
    const float* w_e           = (const float*)d_in[11];
    const float* att           = (const float*)d_in[12];
    const float* bias          = (const float*)d_in[13];

    // workspace (~30 MB):
    u16*   xb      = (u16*)d_ws;                           // NN*DD bf16 (layer input)
    u16*   xl      = xb + (size_t)NN * DD;                 // NN*DD bf16
    u16*   xr      = xl + (size_t)NN * DD;                 // NN*DD bf16
    u16*   erel    = xr + (size_t)NN * DD;                 // LL*RR*DD bf16
    u16*   wt      = erel + (size_t)LL * RR * DD;          // WTOT bf16
    u32*   dstorder= (u32*)(wt + WTOT);                    // EE u32 (src|type, dst-order)
    int*   counts  = (int*)(dstorder + (size_t)EE);        // NN int
    int*   fill    = counts + NN;                          // NN int
    int*   offsets = fill + NN;                            // NN+1 int
    int*   bsum    = offsets + NN + 1;                     // SB int

    // ---- prep: zero counts+fill, then fused hist | wconv | relproj
    hipMemsetAsync(counts, 0, (size_t)NN * 2 * sizeof(int), stream);
    prep_kernel<<<HB + WB + RB, 256, 0, stream>>>(
        edge_index, counts, proj_w, w_l, w_r, wt, rel_emb, w_e, erel);

    // ---- CSR: hierarchical scan + packed scatter (edges constant across layers)
    scan_local_kernel<<<SB, 256, 0, stream>>>(counts, offsets, bsum);
    scan_bsum_kernel<<<1, 256, 0, stream>>>(bsum);
    scan_add_kernel<<<SB, 256, 0, stream>>>(offsets, bsum);
    scatter_kernel<<<(EE + 255) / 256, 256, 0, stream>>>(
        edge_index, edge_type, offsets, fill, dstorder);

    const u16* wtProj = wt;
    const int GB = (NN + 127) / 128;
    gemm_mfma_kernel<false, true><<<dim3(GB, 1), 256, 0, stream>>>(
        node_features, entity, FF, PK, FF, PK,
        wtProj, proj_b, xb, wtProj, proj_b, xb, NN);

    for (int l = 0; l < LL; l++) {
        const u16* wtl = wt + 128 * PK + l * 16384;
        const u16* wtr = wt + 128 * PK + 32768 + l * 16384;
        gemm_mfma_kernel<true, false><<<dim3(GB, 2), 256, 0, stream>>>(
            xb, nullptr, DD, DD, DD, DD,
            wtl, b_l + l * DD, xl,
            wtr, b_r + l * DD, xr, NN);

        node_kernel<<<(NN + 3) / 4, 256, 0, stream>>>(
            dstorder, offsets, xl, xr, erel + (size_t)l * RR * DD,
            att + (size_t)l * DD, bias + (size_t)l * DD,
            xb, (float*)d_out, l == LL - 1);
    }
}